// Round 14
// baseline (1250.238 us; speedup 1.0000x reference)
//
#include <hip/hip_runtime.h>
#include <hip/hip_bf16.h>

// FlashFFN: y = nan_to_num(gelu_tanh(x@W1 + b1) @ W2) + b2
// Round 16: 32x32x16 MFMA SHAPE on the r13 base (best: 1074.2us; r15
// stagger regressed -> dropped). Mechanism: 32x32 ceiling 2382-2495 TF vs
// 2075 for 16x16 (-15% pipe floor) and HALF the MFMA instructions (32 vs
// 64 per wave per K64) -> shorter MFMA bursts, more 2-wave/SIMD slack to
// hide LDS under. Wave = 128x64 out as 4 m-tiles x 2 n-tiles of 32x32;
// K64 = 4 ksteps of 16. Per-phase read-group sizes (A-half 8 b128,
// B-half 4 b128) are IDENTICAL to r13 -> same lgkm/vmcnt ledger, same
// staging, same band map. Swizzled addr algebra: addr(ks) = base^(ks<<5)
// (disjoint bits). Lanes 0-7 hit 8 distinct 16B slots -> conflict-free.
// C/D layout (m74/m101): col=lane&31, row=(reg&3)+8*(reg>>2)+4*(lane>>5).

using bf16 = __hip_bfloat16;
typedef __attribute__((ext_vector_type(16))) float floatx16;
typedef __attribute__((ext_vector_type(8))) short shortx8;

#define TOKENS 4096   // B*S = 2*2048
#define DMODEL 4096
#define DFF    16384

__device__ __forceinline__ void gload_lds16(const void* g, void* l) {
  __builtin_amdgcn_global_load_lds(
      (const __attribute__((address_space(1))) unsigned int*)g,
      (__attribute__((address_space(3))) unsigned int*)l,
      16, 0, 0);
}

__device__ __forceinline__ unsigned lds_u32(const void* p) {
  return (unsigned)(unsigned long long)(const __attribute__((address_space(3))) char*)p;
}

__device__ __forceinline__ float gelu_tanh(float x) {
  // JAX default gelu (approximate=True, tanh form)
  float z = 0.7978845608028654f * (x + 0.044715f * x * x * x);
  float e = __expf(2.0f * z);   // inf -> t=1, 0 -> t=-1: both limits correct
  float t = 1.0f - 2.0f / (e + 1.0f);
  return 0.5f * x * (1.0f + t);
}

#define DSR(dst, addr, off) \
  asm volatile("ds_read_b128 %0, %1 offset:" #off : "=v"(dst) : "v"(addr))

// ---- pre-pass: f32 -> bf16 cast (layout preserved), 8 elems/thread ----
__global__ void cvt_f32_bf16(const float* __restrict__ in, bf16* __restrict__ out) {
  int i = (blockIdx.x * blockDim.x + threadIdx.x) * 8;
  float4 a = *(const float4*)(in + i);
  float4 b = *(const float4*)(in + i + 4);
  union { shortx8 v; bf16 h[8]; } r;
  r.h[0] = __float2bfloat16(a.x); r.h[1] = __float2bfloat16(a.y);
  r.h[2] = __float2bfloat16(a.z); r.h[3] = __float2bfloat16(a.w);
  r.h[4] = __float2bfloat16(b.x); r.h[5] = __float2bfloat16(b.y);
  r.h[6] = __float2bfloat16(b.z); r.h[7] = __float2bfloat16(b.w);
  *(shortx8*)(out + i) = r.v;
}

// ---- pre-pass: transpose + cast. in [R][C] f32 -> out [C][R] bf16 ----
__global__ void transpose_cvt(const float* __restrict__ in, bf16* __restrict__ out,
                              int R, int C) {
  __shared__ float tile[64][65];
  const int c0 = blockIdx.x * 64, r0 = blockIdx.y * 64;
  const int t = threadIdx.x;
#pragma unroll
  for (int p = 0; p < 4; ++p) {
    int r = p * 16 + (t >> 4);
    int c = (t & 15) * 4;
    float4 v = *(const float4*)(in + (size_t)(r0 + r) * C + c0 + c);
    tile[r][c] = v.x; tile[r][c + 1] = v.y;
    tile[r][c + 2] = v.z; tile[r][c + 3] = v.w;
  }
  __syncthreads();
#pragma unroll
  for (int p = 0; p < 2; ++p) {
    int c = p * 32 + (t >> 3);
    int rb = (t & 7) * 8;
    union { shortx8 v; bf16 h[8]; } u;
#pragma unroll
    for (int j = 0; j < 8; ++j) u.h[j] = __float2bfloat16(tile[rb + j][c]);
    *(shortx8*)(out + (size_t)(c0 + c) * R + r0 + rb) = u.v;
  }
}

// kk-grouped 32x32 cluster: 8 MFMA, ks-outer (dep distance 2; r13 showed
// dep order is not binding). Per-acc ks order 0->3 sequential.
#define CLUSTER32(AF, BF, MO, NO) \
  __builtin_amdgcn_sched_barrier(0); \
  __builtin_amdgcn_s_setprio(1); \
  _Pragma("unroll") \
  for (int ks = 0; ks < 4; ++ks) \
    _Pragma("unroll") \
    for (int mt = 0; mt < 2; ++mt) \
      acc[(MO) + mt][NO] = __builtin_amdgcn_mfma_f32_32x32x16_bf16( \
          AF[mt][ks], BF[ks], acc[(MO) + mt][NO], 0, 0, 0); \
  __builtin_amdgcn_s_setprio(0); \
  __builtin_amdgcn_sched_barrier(0);

// ---- BK=64 deep-pipelined GEMM, 32x32x16 MFMA: C = A @ Bt^T ----
template <int FUSE_GELU>
__launch_bounds__(512, 2)
__global__ void gemm_bt(const bf16* __restrict__ A, const bf16* __restrict__ Bt,
                        const float* __restrict__ bias, void* __restrict__ Cout,
                        int M, int N, int K) {
  // [dbuf][half][128][64] bf16 each
  __shared__ __align__(16) bf16 As[2 * 2 * 128 * 64];   // 64 KiB
  __shared__ __align__(16) bf16 Bs[2 * 2 * 128 * 64];   // 64 KiB

  const int tid = threadIdx.x;
  const int wave = tid >> 6;
  const int lane = tid & 63;

  // LLC-aware band mapping (r6, kept): nwg % 256 == 0 for both GEMMs.
  const int wg8  = blockIdx.x & 255;
  const int xcd  = wg8 & 7;
  const int slot = wg8 >> 3;
  const int m0 = (2 * xcd + (slot & 1)) * 256;
  const int n0 = ((blockIdx.x >> 8) * 16 + (slot >> 1)) * 256;

  const size_t Ks = (size_t)K;
  const int NT = K >> 6;   // # of BK=64 K-tiles (64 or 256 here)

  // ---- staging addressing (r9, proven): 8 contiguous rows x 128 B ----
  const int swz = (lane & 7) ^ ((lane >> 3) & 7);
  const bf16* agp = A  + (size_t)(m0 + wave * 8 + (lane >> 3)) * Ks + swz * 8;
  const bf16* bgp = Bt + (size_t)(n0 + wave * 8 + (lane >> 3)) * Ks + swz * 8;

  // ---- fragment-read addressing (32x32x16) ----
  // Wave tiling: rows = wr*32 + mt*64 (mt 0..3; mt0,1 in h0, mt2,3 in h1);
  // cols = wc*32 + nt*128 (nt0 h0, nt1 h1). Operand layout: lane l -> row
  // l&31, k = ks*16 + (l>>5)*8 + 0..7. Stored 16B-blk = (2ks+(l>>5)) ^
  // (row&7); addr(ks) = base ^ (ks<<5) (bits 5-6 hold s>>1, no carries).
  const int wr = wave >> 2, wc = wave & 3;   // 2M x 4N
  const int l31 = lane & 31;
  const int hi  = lane >> 5;
  const int s   = lane & 7;
  const unsigned As0 = lds_u32(As);
  const unsigned Bs0 = lds_u32(Bs);
  const unsigned aBase = As0 + (unsigned)((wr * 32 + l31) * 128 +
                         ((hi ^ (s & 1)) << 4) + ((s >> 1) << 5));
  const unsigned bBase = Bs0 + (unsigned)((wc * 32 + l31) * 128 +
                         ((hi ^ (s & 1)) << 4) + ((s >> 1) << 5));

  floatx16 acc[4][2] = {};           // [mt][nt], 128 f32/lane total
  shortx8 A0[2][4], A1[2][4], B0[4], B1[4];   // [mt][ks] / [ks]

  // ---- prologue: stage tile 0 (A-h0,B-h0,A-h1,B-h1) + B-h0(tile 1) ----
  {
    bf16* lA = As + wave * 512;
    bf16* lB = Bs + wave * 512;
    gload_lds16(agp,             lA);
    gload_lds16(agp +  64 * Ks,  lA + 4096);
    gload_lds16(bgp,             lB);
    gload_lds16(bgp +  64 * Ks,  lB + 4096);
    gload_lds16(agp + 128 * Ks,  lA + 8192);
    gload_lds16(agp + 192 * Ks,  lA + 12288);
    gload_lds16(bgp + 128 * Ks,  lB + 8192);
    gload_lds16(bgp + 192 * Ks,  lB + 12288);
    if (NT > 1) {   // ph4(-1) event: B-h0(tile 1) into dbuf 1
      bf16* lB1 = Bs + 16384 + wave * 512;
      const bf16* gB1 = bgp + 64;
      gload_lds16(gB1,           lB1);
      gload_lds16(gB1 + 64 * Ks, lB1 + 4096);
    }
  }
  if (NT > 1) asm volatile("s_waitcnt vmcnt(4)");
  else        asm volatile("s_waitcnt vmcnt(2)");
  __builtin_amdgcn_s_barrier();
  // prologue reads: B0(0) then A0(0) — FIFO order matches steady state
  {
    unsigned bx;
    bx = bBase;        DSR(B0[0], bx, 0);
    bx = bBase ^ 32u;  DSR(B0[1], bx, 0);
    bx = bBase ^ 64u;  DSR(B0[2], bx, 0);
    bx = bBase ^ 96u;  DSR(B0[3], bx, 0);
    unsigned ax;
    ax = aBase;        DSR(A0[0][0], ax, 0); DSR(A0[1][0], ax, 8192);
    ax = aBase ^ 32u;  DSR(A0[0][1], ax, 0); DSR(A0[1][1], ax, 8192);
    ax = aBase ^ 64u;  DSR(A0[0][2], ax, 0); DSR(A0[1][2], ax, 8192);
    ax = aBase ^ 96u;  DSR(A0[0][3], ax, 0); DSR(A0[1][3], ax, 8192);
  }

  for (int t = 0; t < NT; ++t) {
    const unsigned dsel  = (unsigned)(t & 1) << 15;
    const unsigned dseln = (unsigned)((t + 1) & 1) << 15;
    const unsigned a0d = aBase + dsel;
    const unsigned b0d = bBase + dsel;
    const bool st  = (t + 1 < NT);
    const bool st2 = (t + 2 < NT);
    const bf16* gA = agp + (size_t)(t + 1) * 64;
    bf16* lA = As + ((t + 1) & 1) * 16384 + wave * 512;
    bf16* lB = Bs + ((t + 1) & 1) * 16384 + wave * 512;

    // ===== ph1: Q1 = A-h0 x B-h0 -> acc[0..1][0]; pre-read A-h1(t);
    //        stage A-h0(t+1) [WAR: A-h0(t-1) reads drained ph1(t-1)] =====
    {
      unsigned ax;
      ax = a0d;        DSR(A1[0][0], ax, 16384); DSR(A1[1][0], ax, 24576);
      ax = a0d ^ 32u;  DSR(A1[0][1], ax, 16384); DSR(A1[1][1], ax, 24576);
      ax = a0d ^ 64u;  DSR(A1[0][2], ax, 16384); DSR(A1[1][2], ax, 24576);
      ax = a0d ^ 96u;  DSR(A1[0][3], ax, 16384); DSR(A1[1][3], ax, 24576);
    }
    if (st) { gload_lds16(gA, lA); gload_lds16(gA + 64 * Ks, lA + 4096); }
    asm volatile("s_waitcnt lgkmcnt(8)");   // drain B0(t),A0(t); A1 flies
    CLUSTER32(A0, B0, 0, 0)
    if (st) asm volatile("s_waitcnt vmcnt(4)");   // publish B-h1(t)
    else    asm volatile("s_waitcnt vmcnt(0)");
    __builtin_amdgcn_s_barrier();

    // ===== ph2: Q2 = A-h1 x B-h0 -> acc[2..3][0]; pre-read B-h1(t);
    //        stage A-h1(t+1) [WAR: A1(t-1) reads drained ph2(t-1)] =====
    {
      unsigned bx;
      bx = b0d;        DSR(B1[0], bx, 16384);
      bx = b0d ^ 32u;  DSR(B1[1], bx, 16384);
      bx = b0d ^ 64u;  DSR(B1[2], bx, 16384);
      bx = b0d ^ 96u;  DSR(B1[3], bx, 16384);
    }
    if (st) { gload_lds16(gA + 128 * Ks, lA + 8192); gload_lds16(gA + 192 * Ks, lA + 12288); }
    asm volatile("s_waitcnt lgkmcnt(4)");   // drain A1(t); B1 flies
    CLUSTER32(A1, B0, 2, 0)
    if (st) asm volatile("s_waitcnt vmcnt(4)");   // publish B-h0(t+1)
    __builtin_amdgcn_s_barrier();

    // ===== ph3: Q3 = A-h1 x B-h1 -> acc[2..3][1]; pre-read B-h0(t+1);
    //        stage B-h1(t+1) [WAR: B1(t-1) reads drained ph3(t-1)] =====
    if (st) {
      const bf16* gB = bgp + (size_t)(t + 1) * 64;
      const unsigned bnd = bBase + dseln;
      unsigned bx;
      bx = bnd;        DSR(B0[0], bx, 0);
      bx = bnd ^ 32u;  DSR(B0[1], bx, 0);
      bx = bnd ^ 64u;  DSR(B0[2], bx, 0);
      bx = bnd ^ 96u;  DSR(B0[3], bx, 0);
      gload_lds16(gB + 128 * Ks, lB + 8192);
      gload_lds16(gB + 192 * Ks, lB + 12288);
      asm volatile("s_waitcnt lgkmcnt(4)");   // drain B1(t); B0(t+1) flies
    } else {
      asm volatile("s_waitcnt lgkmcnt(0)");   // drain B1(t)
    }
    CLUSTER32(A1, B1, 2, 1)
    if (st) asm volatile("s_waitcnt vmcnt(4)");   // publish A-h0(t+1)
    __builtin_amdgcn_s_barrier();

    // ===== ph4: Q4 = A-h0 x B-h1 -> acc[0..1][1];
    //        stage B-h0(t+2) [WAR: B0(t) reads drained ph1(t)];
    //        post-read A-h0(t+1) =====
    if (st2) {
      const bf16* gB2 = bgp + (size_t)(t + 2) * 64;
      bf16* lB2 = Bs + (t & 1) * 16384 + wave * 512;   // (t+2)&1 == t&1
      gload_lds16(gB2,           lB2);
      gload_lds16(gB2 + 64 * Ks, lB2 + 4096);
    }
    CLUSTER32(A0, B1, 0, 1)
    if (st) {   // post-read A0(t+1); drains at ph1(t+1) lgkm(8)
      const unsigned and_ = aBase + dseln;
      unsigned ax;
      ax = and_;        DSR(A0[0][0], ax, 0); DSR(A0[1][0], ax, 8192);
      ax = and_ ^ 32u;  DSR(A0[0][1], ax, 0); DSR(A0[1][1], ax, 8192);
      ax = and_ ^ 64u;  DSR(A0[0][2], ax, 0); DSR(A0[1][2], ax, 8192);
      ax = and_ ^ 96u;  DSR(A0[0][3], ax, 0); DSR(A0[1][3], ax, 8192);
    }
    if (st2)     asm volatile("s_waitcnt vmcnt(4)");  // publish A-h1(t+1)
    else if (st) asm volatile("s_waitcnt vmcnt(2)");
    __builtin_amdgcn_s_barrier();
  }

  // epilogue. 32x32 C/D layout (m74/m101): col = lane&31,
  // row = (reg&3) + 8*(reg>>2) + 4*(lane>>5).
  // tiles: row = m0 + wr*32 + (mt&1)*64 + (mt>>1)*128 + tile_row,
  //        col = n0 + wc*32 + nt*128 + (lane&31).
  const int colb = n0 + wc * 32 + l31;
  const int rowb = m0 + wr * 32 + 4 * hi;
#pragma unroll
  for (int nt = 0; nt < 2; ++nt) {
    const int col = colb + nt * 128;
    const float bv = bias[col];
#pragma unroll
    for (int mt = 0; mt < 4; ++mt) {
      const int rb2 = rowb + (mt & 1) * 64 + (mt >> 1) * 128;
#pragma unroll
      for (int reg = 0; reg < 16; ++reg) {
        const int row = rb2 + (reg & 3) + 8 * (reg >> 2);
        float v = acc[mt][nt][reg];
        if (FUSE_GELU) {
          v = gelu_tanh(v + bv);
          ((bf16*)Cout)[(size_t)row * N + col] = __float2bfloat16(v);
        } else {
          if (!isfinite(v)) v = 0.0f;   // nan_to_num BEFORE +b2
          ((float*)Cout)[(size_t)row * N + col] = v + bv;
        }
      }
    }
  }
}

extern "C" void kernel_launch(void* const* d_in, const int* in_sizes, int n_in,
                              void* d_out, int out_size, void* d_ws, size_t ws_size,
                              hipStream_t stream) {
  const float* x  = (const float*)d_in[0];
  const float* W1 = (const float*)d_in[1];
  const float* b1 = (const float*)d_in[2];
  const float* W2 = (const float*)d_in[3];
  const float* b2 = (const float*)d_in[4];
  float* out = (float*)d_out;

  // workspace layout (bf16): xb 32MB @0, h 128MB @32MB, w1t 128MB @160MB,
  // w2t 128MB @288MB (total 416 MB)
  char* ws = (char*)d_ws;
  bf16* xb  = (bf16*)(ws);
  bf16* h   = (bf16*)(ws + (size_t)32  * 1024 * 1024);
  bf16* w1t = (bf16*)(ws + (size_t)160 * 1024 * 1024);
  bf16* w2t = (bf16*)(ws + (size_t)288 * 1024 * 1024);

  cvt_f32_bf16<<<(TOKENS * DMODEL / 8) / 256, 256, 0, stream>>>(x, xb);
  transpose_cvt<<<dim3(DFF / 64, DMODEL / 64), 256, 0, stream>>>(W1, w1t, DMODEL, DFF);
  transpose_cvt<<<dim3(DMODEL / 64, DFF / 64), 256, 0, stream>>>(W2, w2t, DFF, DMODEL);

  // GEMM1: h = gelu(x @ W1 + b1)   [4096 x 16384] bf16
  gemm_bt<1><<<dim3((DFF / 256) * (TOKENS / 256)), 512, 0, stream>>>(
      xb, w1t, b1, h, TOKENS, DFF, DMODEL);

  // GEMM2: out = nan_guard(h @ W2) + b2   [4096 x 4096] f32
  gemm_bt<0><<<dim3((DMODEL / 256) * (TOKENS / 256)), 512, 0, stream>>>(
      h, w2t, b2, out, TOKENS, DMODEL, DFF);
}

// Round 15
// 1075.801 us; speedup vs baseline: 1.1621x; 1.1621x over previous
//
#include <hip/hip_runtime.h>
#include <hip/hip_bf16.h>

// FlashFFN: y = nan_to_num(gelu_tanh(x@W1 + b1) @ W2) + b2
// Round 17: REVERT to r13 (session best: 1074.2us; 985 TF/GEMM).
// r16 (32x32 MFMA) regressed via SQ_LDS_BANK_CONFLICT 0 -> 5.03e7: the
// r9 swizzle is conflict-free ONLY for the 16x16 read pattern (Guideline
// 21: swizzle and read pattern must be co-designed). r15 (wave stagger)
// and r14 (de-wall -> spills) also regressed. Probed-and-closed axes:
// choreography, LLC band map, staging datapath (BK=64 = the big win),
// read-ahead lgkm, occupancy (reg-capped at 8 waves/CU), vmcnt depth,
// MFMA dep order, MFMA shape. This structure's floor is ~5200 cyc/K64
// at MfmaUtil 44%, HBM 16%, conflicts 0.

using bf16 = __hip_bfloat16;
typedef __attribute__((ext_vector_type(4))) float floatx4;
typedef __attribute__((ext_vector_type(8))) short shortx8;

#define TOKENS 4096   // B*S = 2*2048
#define DMODEL 4096
#define DFF    16384

__device__ __forceinline__ void gload_lds16(const void* g, void* l) {
  __builtin_amdgcn_global_load_lds(
      (const __attribute__((address_space(1))) unsigned int*)g,
      (__attribute__((address_space(3))) unsigned int*)l,
      16, 0, 0);
}

__device__ __forceinline__ unsigned lds_u32(const void* p) {
  return (unsigned)(unsigned long long)(const __attribute__((address_space(3))) char*)p;
}

__device__ __forceinline__ float gelu_tanh(float x) {
  // JAX default gelu (approximate=True, tanh form)
  float z = 0.7978845608028654f * (x + 0.044715f * x * x * x);
  float e = __expf(2.0f * z);   // inf -> t=1, 0 -> t=-1: both limits correct
  float t = 1.0f - 2.0f / (e + 1.0f);
  return 0.5f * x * (1.0f + t);
}

#define DSR(dst, addr, off) \
  asm volatile("ds_read_b128 %0, %1 offset:" #off : "=v"(dst) : "v"(addr))

// ---- pre-pass: f32 -> bf16 cast (layout preserved), 8 elems/thread ----
__global__ void cvt_f32_bf16(const float* __restrict__ in, bf16* __restrict__ out) {
  int i = (blockIdx.x * blockDim.x + threadIdx.x) * 8;
  float4 a = *(const float4*)(in + i);
  float4 b = *(const float4*)(in + i + 4);
  union { shortx8 v; bf16 h[8]; } r;
  r.h[0] = __float2bfloat16(a.x); r.h[1] = __float2bfloat16(a.y);
  r.h[2] = __float2bfloat16(a.z); r.h[3] = __float2bfloat16(a.w);
  r.h[4] = __float2bfloat16(b.x); r.h[5] = __float2bfloat16(b.y);
  r.h[6] = __float2bfloat16(b.z); r.h[7] = __float2bfloat16(b.w);
  *(shortx8*)(out + i) = r.v;
}

// ---- pre-pass: transpose + cast. in [R][C] f32 -> out [C][R] bf16 ----
__global__ void transpose_cvt(const float* __restrict__ in, bf16* __restrict__ out,
                              int R, int C) {
  __shared__ float tile[64][65];
  const int c0 = blockIdx.x * 64, r0 = blockIdx.y * 64;
  const int t = threadIdx.x;
#pragma unroll
  for (int p = 0; p < 4; ++p) {
    int r = p * 16 + (t >> 4);
    int c = (t & 15) * 4;
    float4 v = *(const float4*)(in + (size_t)(r0 + r) * C + c0 + c);
    tile[r][c] = v.x; tile[r][c + 1] = v.y;
    tile[r][c + 2] = v.z; tile[r][c + 3] = v.w;
  }
  __syncthreads();
#pragma unroll
  for (int p = 0; p < 2; ++p) {
    int c = p * 32 + (t >> 3);
    int rb = (t & 7) * 8;
    union { shortx8 v; bf16 h[8]; } u;
#pragma unroll
    for (int j = 0; j < 8; ++j) u.h[j] = __float2bfloat16(tile[rb + j][c]);
    *(shortx8*)(out + (size_t)(c0 + c) * R + r0 + rb) = u.v;
  }
}

// ---- BK=64 deep-pipelined GEMM, 3-phase staging slack: C = A @ Bt^T ----
template <int FUSE_GELU>
__launch_bounds__(512, 2)
__global__ void gemm_bt(const bf16* __restrict__ A, const bf16* __restrict__ Bt,
                        const float* __restrict__ bias, void* __restrict__ Cout,
                        int M, int N, int K) {
  // [dbuf][half][128][64] bf16 each
  __shared__ __align__(16) bf16 As[2 * 2 * 128 * 64];   // 64 KiB
  __shared__ __align__(16) bf16 Bs[2 * 2 * 128 * 64];   // 64 KiB

  const int tid = threadIdx.x;
  const int wave = tid >> 6;
  const int lane = tid & 63;

  // LLC-aware band mapping (r6, kept): nwg % 256 == 0 for both GEMMs.
  const int wg8  = blockIdx.x & 255;
  const int xcd  = wg8 & 7;
  const int slot = wg8 >> 3;
  const int m0 = (2 * xcd + (slot & 1)) * 256;
  const int n0 = ((blockIdx.x >> 8) * 16 + (slot >> 1)) * 256;

  const size_t Ks = (size_t)K;
  const int NT = K >> 6;   // # of BK=64 K-tiles (64 or 256 here)

  // ---- staging addressing (r9, proven): 8 contiguous rows x 128 B ----
  const int swz = (lane & 7) ^ ((lane >> 3) & 7);
  const bf16* agp = A  + (size_t)(m0 + wave * 8 + (lane >> 3)) * Ks + swz * 8;
  const bf16* bgp = Bt + (size_t)(n0 + wave * 8 + (lane >> 3)) * Ks + swz * 8;

  // ---- fragment-read addressing (r9, proven) ----
  const int wr = wave >> 2, wc = wave & 3;   // 2M x 4N
  const int fr = lane & 15;
  const int q  = lane >> 4;
  const unsigned As0 = lds_u32(As);
  const unsigned Bs0 = lds_u32(Bs);
  const unsigned aK0 = As0 + (unsigned)((wr * 16 + fr) * 128 +
                       (((fr >> 2) & 1) * 64) + ((q ^ (fr & 3)) * 16));
  const unsigned aK1 = aK0 ^ 64u;
  const unsigned bK0 = Bs0 + (unsigned)((wc * 16 + fr) * 128 +
                       (((fr >> 2) & 1) * 64) + ((q ^ (fr & 3)) * 16));
  const unsigned bK1 = bK0 ^ 64u;

  floatx4 acc[8][4] = {};
  shortx8 A0[2][4], A1[2][4], B0[2][2], B1[2][2];   // persistent fragments

  // ---- prologue: stage tile 0 (A-h0,B-h0,A-h1,B-h1) + B-h0(tile 1) ----
  {
    bf16* lA = As + wave * 512;
    bf16* lB = Bs + wave * 512;
    gload_lds16(agp,             lA);
    gload_lds16(agp +  64 * Ks,  lA + 4096);
    gload_lds16(bgp,             lB);
    gload_lds16(bgp +  64 * Ks,  lB + 4096);
    gload_lds16(agp + 128 * Ks,  lA + 8192);
    gload_lds16(agp + 192 * Ks,  lA + 12288);
    gload_lds16(bgp + 128 * Ks,  lB + 8192);
    gload_lds16(bgp + 192 * Ks,  lB + 12288);
    if (NT > 1) {   // ph4(-1) event: B-h0(tile 1) into dbuf 1
      bf16* lB1 = Bs + 16384 + wave * 512;
      const bf16* gB1 = bgp + 64;
      gload_lds16(gB1,           lB1);
      gload_lds16(gB1 + 64 * Ks, lB1 + 4096);
    }
  }
  // queue: [Ah0(2),Bh0(2),Ah1(2),Bh1(2),Bh0n(2)] -> drain to 4:
  // Ah0,Bh0 (prologue reads) + Ah1 (ph1 reads) resident; Bh1,Bh0n fly.
  if (NT > 1) asm volatile("s_waitcnt vmcnt(4)");
  else        asm volatile("s_waitcnt vmcnt(2)");
  __builtin_amdgcn_s_barrier();
  // prologue reads: B0(0) then A0(0) — FIFO order matches steady state
  DSR(B0[0][0], bK0, 0); DSR(B0[0][1], bK0, 8192);
  DSR(B0[1][0], bK1, 0); DSR(B0[1][1], bK1, 8192);
  DSR(A0[0][0], aK0, 0);     DSR(A0[0][1], aK0, 4096);
  DSR(A0[0][2], aK0, 8192);  DSR(A0[0][3], aK0, 12288);
  DSR(A0[1][0], aK1, 0);     DSR(A0[1][1], aK1, 4096);
  DSR(A0[1][2], aK1, 8192);  DSR(A0[1][3], aK1, 12288);

  for (int t = 0; t < NT; ++t) {
    const unsigned dsel  = (unsigned)(t & 1) << 15;
    const unsigned dseln = (unsigned)((t + 1) & 1) << 15;
    const unsigned a0 = aK0 + dsel,  a1 = aK1 + dsel;
    const unsigned b0 = bK0 + dsel,  b1 = bK1 + dsel;
    const unsigned an0 = aK0 + dseln, an1 = aK1 + dseln;
    const unsigned bn0 = bK0 + dseln, bn1 = bK1 + dseln;
    const bool st  = (t + 1 < NT);
    const bool st2 = (t + 2 < NT);
    const bf16* gA = agp + (size_t)(t + 1) * 64;
    bf16* lA = As + ((t + 1) & 1) * 16384 + wave * 512;
    bf16* lB = Bs + ((t + 1) & 1) * 16384 + wave * 512;

    // ===== ph1: Q1 = A0·B0 -> acc[0..3][0..1]; pre-read A1(t);
    //        stage A-h0(t+1) [WAR: A-h0(t-1) reads drained ph1(t-1)] =====
    DSR(A1[0][0], a0, 16384); DSR(A1[0][1], a0, 20480);
    DSR(A1[0][2], a0, 24576); DSR(A1[0][3], a0, 28672);
    DSR(A1[1][0], a1, 16384); DSR(A1[1][1], a1, 20480);
    DSR(A1[1][2], a1, 24576); DSR(A1[1][3], a1, 28672);
    if (st) { gload_lds16(gA, lA); gload_lds16(gA + 64 * Ks, lA + 4096); }
    asm volatile("s_waitcnt lgkmcnt(8)");   // drain B0(t),A0(t); A1 flies
    __builtin_amdgcn_sched_barrier(0);
    __builtin_amdgcn_s_setprio(1);
    // kk-grouped: 8 independent kk0, then 8 kk1 (dep distance 8 slots)
#pragma unroll
    for (int f = 0; f < 4; ++f)
#pragma unroll
      for (int n = 0; n < 2; ++n)
        acc[f][n] = __builtin_amdgcn_mfma_f32_16x16x32_bf16(A0[0][f], B0[0][n], acc[f][n], 0, 0, 0);
#pragma unroll
    for (int f = 0; f < 4; ++f)
#pragma unroll
      for (int n = 0; n < 2; ++n)
        acc[f][n] = __builtin_amdgcn_mfma_f32_16x16x32_bf16(A0[1][f], B0[1][n], acc[f][n], 0, 0, 0);
    __builtin_amdgcn_s_setprio(0);
    __builtin_amdgcn_sched_barrier(0);
    // publish B-h1(t) (issued ph3(t-1), 3 phases slack):
    if (st) asm volatile("s_waitcnt vmcnt(4)");
    else    asm volatile("s_waitcnt vmcnt(0)");
    __builtin_amdgcn_s_barrier();

    // ===== ph2: Q2 = A1·B0 -> acc[4..7][0..1]; pre-read B1(t);
    //        stage A-h1(t+1) [WAR: A1(t-1) reads drained ph2(t-1)] =====
    DSR(B1[0][0], b0, 16384); DSR(B1[0][1], b0, 24576);
    DSR(B1[1][0], b1, 16384); DSR(B1[1][1], b1, 24576);
    if (st) { gload_lds16(gA + 128 * Ks, lA + 8192); gload_lds16(gA + 192 * Ks, lA + 12288); }
    asm volatile("s_waitcnt lgkmcnt(4)");   // drain A1(t); B1 flies
    __builtin_amdgcn_sched_barrier(0);
    __builtin_amdgcn_s_setprio(1);
#pragma unroll
    for (int f = 0; f < 4; ++f)
#pragma unroll
      for (int n = 0; n < 2; ++n)
        acc[4 + f][n] = __builtin_amdgcn_mfma_f32_16x16x32_bf16(A1[0][f], B0[0][n], acc[4 + f][n], 0, 0, 0);
#pragma unroll
    for (int f = 0; f < 4; ++f)
#pragma unroll
      for (int n = 0; n < 2; ++n)
        acc[4 + f][n] = __builtin_amdgcn_mfma_f32_16x16x32_bf16(A1[1][f], B0[1][n], acc[4 + f][n], 0, 0, 0);
    __builtin_amdgcn_s_setprio(0);
    __builtin_amdgcn_sched_barrier(0);
    // publish B-h0(t+1) (issued ph4(t-1), 3 phases slack):
    if (st) asm volatile("s_waitcnt vmcnt(4)");
    __builtin_amdgcn_s_barrier();

    // ===== ph3: Q3 = A1·B1 -> acc[4..7][2..3]; pre-read B0(t+1);
    //        stage B-h1(t+1) [WAR: B1(t-1) reads drained ph3(t-1)] =====
    if (st) {
      const bf16* gB = bgp + (size_t)(t + 1) * 64;
      DSR(B0[0][0], bn0, 0); DSR(B0[0][1], bn0, 8192);
      DSR(B0[1][0], bn1, 0); DSR(B0[1][1], bn1, 8192);
      gload_lds16(gB + 128 * Ks, lB + 8192);
      gload_lds16(gB + 192 * Ks, lB + 12288);
      asm volatile("s_waitcnt lgkmcnt(4)");   // drain B1(t); B0(t+1) flies
    } else {
      asm volatile("s_waitcnt lgkmcnt(0)");   // drain B1(t)
    }
    __builtin_amdgcn_sched_barrier(0);
    __builtin_amdgcn_s_setprio(1);
#pragma unroll
    for (int f = 0; f < 4; ++f)
#pragma unroll
      for (int n = 0; n < 2; ++n)
        acc[4 + f][2 + n] = __builtin_amdgcn_mfma_f32_16x16x32_bf16(A1[0][f], B1[0][n], acc[4 + f][2 + n], 0, 0, 0);
#pragma unroll
    for (int f = 0; f < 4; ++f)
#pragma unroll
      for (int n = 0; n < 2; ++n)
        acc[4 + f][2 + n] = __builtin_amdgcn_mfma_f32_16x16x32_bf16(A1[1][f], B1[1][n], acc[4 + f][2 + n], 0, 0, 0);
    __builtin_amdgcn_s_setprio(0);
    __builtin_amdgcn_sched_barrier(0);
    // publish A-h0(t+1) (issued ph1(t), 3 phases slack incl. this one):
    if (st) asm volatile("s_waitcnt vmcnt(4)");
    __builtin_amdgcn_s_barrier();

    // ===== ph4: Q4 = A0·B1 -> acc[0..3][2..3];
    //        stage B-h0(t+2) [WAR: B0(t) reads drained ph1(t)];
    //        post-read A0(t+1) =====
    if (st2) {
      const bf16* gB2 = bgp + (size_t)(t + 2) * 64;
      bf16* lB2 = Bs + (t & 1) * 16384 + wave * 512;   // (t+2)&1 == t&1
      gload_lds16(gB2,           lB2);
      gload_lds16(gB2 + 64 * Ks, lB2 + 4096);
    }
    __builtin_amdgcn_s_setprio(1);
#pragma unroll
    for (int f = 0; f < 4; ++f)
#pragma unroll
      for (int n = 0; n < 2; ++n)
        acc[f][2 + n] = __builtin_amdgcn_mfma_f32_16x16x32_bf16(A0[0][f], B1[0][n], acc[f][2 + n], 0, 0, 0);
#pragma unroll
    for (int f = 0; f < 4; ++f)
#pragma unroll
      for (int n = 0; n < 2; ++n)
        acc[f][2 + n] = __builtin_amdgcn_mfma_f32_16x16x32_bf16(A0[1][f], B1[1][n], acc[f][2 + n], 0, 0, 0);
    __builtin_amdgcn_s_setprio(0);
    __builtin_amdgcn_sched_barrier(0);
    if (st) {   // post-cluster read-ahead: A0(t+1); drains at ph1(t+1) lgkm(8)
      DSR(A0[0][0], an0, 0);     DSR(A0[0][1], an0, 4096);
      DSR(A0[0][2], an0, 8192);  DSR(A0[0][3], an0, 12288);
      DSR(A0[1][0], an1, 0);     DSR(A0[1][1], an1, 4096);
      DSR(A0[1][2], an1, 8192);  DSR(A0[1][3], an1, 12288);
    }
    // publish A-h1(t+1) (issued ph2(t), 3 phases slack):
    if (st2)     asm volatile("s_waitcnt vmcnt(4)");
    else if (st) asm volatile("s_waitcnt vmcnt(2)");
    __builtin_amdgcn_s_barrier();
  }

  // epilogue. C/D layout (m89/m91): col = lane&15, row = (lane>>4)*4 + reg.
  // strided wave tiling: row = m0+wr*16+mi*32+..., col = n0+wc*16+ni*64+fr
  const int col0 = n0 + wc * 16 + fr;
  const int row0 = m0 + wr * 16 + (lane >> 4) * 4;
#pragma unroll
  for (int ni = 0; ni < 4; ++ni) {
    const int col = col0 + ni * 64;
    const float bv = bias[col];
#pragma unroll
    for (int mi = 0; mi < 8; ++mi) {
#pragma unroll
      for (int r = 0; r < 4; ++r) {
        const int row = row0 + mi * 32 + r;
        float v = acc[mi][ni][r];
        if (FUSE_GELU) {
          v = gelu_tanh(v + bv);
          ((bf16*)Cout)[(size_t)row * N + col] = __float2bfloat16(v);
        } else {
          if (!isfinite(v)) v = 0.0f;   // nan_to_num BEFORE +b2
          ((float*)Cout)[(size_t)row * N + col] = v + bv;
        }
      }
    }
  }
}

extern "C" void kernel_launch(void* const* d_in, const int* in_sizes, int n_in,
                              void* d_out, int out_size, void* d_ws, size_t ws_size,
                              hipStream_t stream) {
  const float* x  = (const float*)d_in[0];
  const float* W1 = (const float*)d_in[1];
  const float* b1 = (const float*)d_in[2];
  const float* W2 = (const float*)d_in[3];
  const float* b2 = (const float*)d_in[4];
  float* out = (float*)d_out;

  // workspace layout (bf16): xb 32MB @0, h 128MB @32MB, w1t 128MB @160MB,
  // w2t 128MB @288MB (total 416 MB)
  char* ws = (char*)d_ws;
  bf16* xb  = (bf16*)(ws);
  bf16* h   = (bf16*)(ws + (size_t)32  * 1024 * 1024);
  bf16* w1t = (bf16*)(ws + (size_t)160 * 1024 * 1024);
  bf16* w2t = (bf16*)(ws + (size_t)288 * 1024 * 1024);

  cvt_f32_bf16<<<(TOKENS * DMODEL / 8) / 256, 256, 0, stream>>>(x, xb);
  transpose_cvt<<<dim3(DFF / 64, DMODEL / 64), 256, 0, stream>>>(W1, w1t, DMODEL, DFF);
  transpose_cvt<<<dim3(DMODEL / 64, DFF / 64), 256, 0, stream>>>(W2, w2t, DFF, DMODEL);

  // GEMM1: h = gelu(x @ W1 + b1)   [4096 x 16384] bf16
  gemm_bt<1><<<dim3((DFF / 256) * (TOKENS / 256)), 512, 0, stream>>>(
      xb, w1t, b1, h, TOKENS, DFF, DMODEL);

  // GEMM2: out = nan_guard(h @ W2) + b2   [4096 x 4096] f32
  gemm_bt<0><<<dim3((DMODEL / 256) * (TOKENS / 256)), 512, 0, stream>>>(
      h, w2t, b2, out, TOKENS, DMODEL, DFF);
}